// Round 5
// baseline (302.442 us; speedup 1.0000x reference)
//
#include <hip/hip_runtime.h>
#include <hip/hip_bf16.h>

// Problem constants (from reference)
#define T_DIM   16
#define N_NODES 10000
#define FIN     32
#define FH      64
#define NE      160000
#define GPB     8              // 32-lane groups per 256-thread block
#define TB      2              // timesteps per chunk
#define NCHUNK  (T_DIM / TB)   // 8 chunks -> one per XCD via bid%8
#define NF      (N_NODES * FIN)

// ---------------------------------------------------------------------------
// Kernel 1: degree (float, weighted, over dst) + in-edge count histogram
// ---------------------------------------------------------------------------
__global__ void build_deg_kernel(const int* __restrict__ ei,
                                 const float* __restrict__ w,
                                 float* __restrict__ deg,
                                 int* __restrict__ cnt) {
    int e = blockIdx.x * blockDim.x + threadIdx.x;
    if (e < NE) {
        int d = ei[NE + e];          // dst row of edge_index (2, E)
        atomicAdd(&deg[d], w[e]);
        atomicAdd(&cnt[d], 1);
    }
}

// ---------------------------------------------------------------------------
// Kernel 2 (merged): blocks 0-9 finish_deg; block 10 exclusive scan;
// blocks 11-12 pack W1/W2 into per-lane float2 column pairs.
// W1p[f*32+l] = {W1[f][l], W1[f][l+32]}   (f<32, l<32)
// W2p[j*32+l] = {W2[j][l], W2[j+32][l]}   (j<32, l<32)
// ---------------------------------------------------------------------------
__global__ __launch_bounds__(1024) void mid_kernel(
    const float* __restrict__ deg, float* __restrict__ dis,
    float* __restrict__ selfn,
    const int* __restrict__ cnt, int* __restrict__ rowptr,
    const float* __restrict__ W1, const float* __restrict__ W2,
    float2* __restrict__ W1p, float2* __restrict__ W2p) {
    __shared__ int sm[1024];
    int b = blockIdx.x;
    int tid = threadIdx.x;
    if (b < 10) {                       // dis / selfnorm
        int n = b * 1024 + tid;
        if (n < N_NODES) {
            float d = deg[n] + 1.0f;    // + self-loop weight
            float r = rsqrtf(d);
            dis[n] = r;
            selfn[n] = r * r;
        }
    } else if (b == 10) {               // exclusive scan cnt -> rowptr
        int base = tid * 10;
        int v[10];
        int s = 0;
#pragma unroll
        for (int k = 0; k < 10; ++k) {
            int i = base + k;
            v[k] = (i < N_NODES) ? cnt[i] : 0;
            s += v[k];
        }
        sm[tid] = s;
        __syncthreads();
        for (int off = 1; off < 1024; off <<= 1) {
            int t = (tid >= off) ? sm[tid - off] : 0;
            __syncthreads();
            sm[tid] += t;
            __syncthreads();
        }
        int run = (tid > 0) ? sm[tid - 1] : 0;
#pragma unroll
        for (int k = 0; k < 10; ++k) {
            int i = base + k;
            if (i <= N_NODES) rowptr[i] = run;
            run += v[k];
        }
    } else if (b == 11) {
        int f = tid >> 5, l = tid & 31;
        W1p[tid] = make_float2(W1[f * FH + l], W1[f * FH + 32 + l]);
    } else {
        int j = tid >> 5, l = tid & 31;
        W2p[tid] = make_float2(W2[j * FIN + l], W2[(j + 32) * FIN + l]);
    }
}

// ---------------------------------------------------------------------------
// Kernel 3: scatter edges into dst-sorted CSR, packed {col, norm-bits}
// ---------------------------------------------------------------------------
__global__ void build_csr_kernel(const int* __restrict__ ei,
                                 const float* __restrict__ w,
                                 const float* __restrict__ dis,
                                 const int* __restrict__ rowptr,
                                 int* __restrict__ cursor,
                                 int2* __restrict__ edges) {
    int e = blockIdx.x * blockDim.x + threadIdx.x;
    if (e < NE) {
        int s = ei[e];
        int d = ei[NE + e];
        int pos = rowptr[d] + atomicAdd(&cursor[d], 1);
        edges[pos] = make_int2(s, __float_as_int(dis[s] * w[e] * dis[d]));
    }
}

// ---------------------------------------------------------------------------
// Kernel 4: transpose x (T,N,F) -> xp[(n*NCHUNK+tc)*32+lane] = {x[t0], x[t0+1]}
// blockIdx = nb*8 + tc so the writing XCD (bid%8) is the one that will
// consume chunk tc in layer1 (lines stay in its L2).
// ---------------------------------------------------------------------------
__global__ __launch_bounds__(256) void transpose_kernel(
    const float* __restrict__ x, float2* __restrict__ xp) {
    int b = blockIdx.x;
    int tc = b & (NCHUNK - 1);
    int nb = b >> 3;
    int grp = threadIdx.x >> 5;
    int lane = threadIdx.x & 31;
    int n = nb * GPB + grp;
    const float* x0 = x + (size_t)(tc * TB) * NF + n * FIN + lane;
    xp[((size_t)n * NCHUNK + tc) * 32 + lane] = make_float2(x0[0], x0[NF]);
}

// Edge-gather macros: acc (a0,a1) += val * src_pair, src from packed float2
#define GFMA(P, Q) { float2 vv = Q[(size_t)(P).x * (NCHUNK * 32)];          \
                     float ww = __int_as_float((P).y);                      \
                     a0 = fmaf(ww, vv.x, a0); a1 = fmaf(ww, vv.y, a1); }

// Software-pipelined CSR gather over row [e0,e1) of packed edges E,
// source table Q (float2*, pre-offset by tc*32+lane).
#define GATHER_LOOP(E, Q)                                                   \
    {                                                                       \
        int i = 0;                                                          \
        int2 c0, c1, c2, c3;                                                \
        if (i + 4 <= len) { c0 = E[0]; c1 = E[1]; c2 = E[2]; c3 = E[3]; }   \
        for (; i + 8 <= len; i += 4) {                                      \
            int2 n0 = E[i + 4], n1 = E[i + 5], n2 = E[i + 6], n3 = E[i + 7];\
            GFMA(c0, Q) GFMA(c1, Q) GFMA(c2, Q) GFMA(c3, Q)                 \
            c0 = n0; c1 = n1; c2 = n2; c3 = n3;                             \
        }                                                                   \
        if (i + 4 <= len) { GFMA(c0, Q) GFMA(c1, Q) GFMA(c2, Q) GFMA(c3, Q) \
                            i += 4; }                                       \
        for (; i < len; ++i) { int2 p = E[i]; GFMA(p, Q) }                  \
    }

// ---------------------------------------------------------------------------
// Kernel 5 (fused layer 1): block = (t-chunk tc, node-block nb),
// blockIdx = nb*8 + tc pins chunk->XCD (per-XCD working set: xp-slice 2.56 MB
// + edges 1.28 MB < 4 MB L2). One 32-lane group per node, TB=2 in registers.
// One float2 load per edge; edges software-pipelined. LDS only for
// wave-private sAcc/sH broadcasts (6 KB) -> NO barriers, high occupancy.
// Weights read from global (packed float2 columns, L1/L2-resident).
// ---------------------------------------------------------------------------
__global__ __launch_bounds__(256) void layer1_kernel(
    const float2* __restrict__ xp,
    const int* __restrict__ rowptr,
    const int2* __restrict__ edges,
    const float* __restrict__ selfn,
    const float2* __restrict__ W1p,
    const float* __restrict__ b1,
    const float2* __restrict__ W2p,
    float2* __restrict__ gp) {
    __shared__ float sAcc[GPB][TB][FIN];   // 2 KB
    __shared__ float sH[GPB][TB][FH];      // 4 KB

    int b = blockIdx.x;
    int tc = b & (NCHUNK - 1);
    int nb = b >> 3;
    int tid = threadIdx.x;
    int grp = tid >> 5;
    int lane = tid & 31;
    int n = nb * GPB + grp;

    const float2* xq = xp + tc * 32 + lane;   // index with [c * 256]

    float sn = selfn[n];
    float2 xs = xq[(size_t)n * (NCHUNK * 32)];
    float a0 = sn * xs.x;
    float a1 = sn * xs.y;

    int e0 = rowptr[n];
    int len = rowptr[n + 1] - e0;
    const int2* E = edges + e0;
    GATHER_LOOP(E, xq)

    // ---- dense: h = relu(acc @ W1 + b1); g = h @ W2 ----
    sAcc[grp][0][lane] = a0;
    sAcc[grp][1][lane] = a1;
    float h0 = b1[lane];
    float h1 = b1[lane + 32];
    float h2 = h0, h3 = h1;
#pragma unroll
    for (int f = 0; f < FIN; ++f) {
        float2 w = W1p[f * 32 + lane];
        float af0 = sAcc[grp][0][f];   // LDS broadcast (free)
        float af1 = sAcc[grp][1][f];
        h0 = fmaf(af0, w.x, h0); h1 = fmaf(af0, w.y, h1);
        h2 = fmaf(af1, w.x, h2); h3 = fmaf(af1, w.y, h3);
    }
    sH[grp][0][lane] = fmaxf(h0, 0.0f);
    sH[grp][0][lane + 32] = fmaxf(h1, 0.0f);
    sH[grp][1][lane] = fmaxf(h2, 0.0f);
    sH[grp][1][lane + 32] = fmaxf(h3, 0.0f);
    float g0 = 0.0f, g1 = 0.0f;
#pragma unroll
    for (int j = 0; j < 32; ++j) {
        float2 w = W2p[j * 32 + lane];
        g0 = fmaf(sH[grp][0][j], w.x, g0);
        g0 = fmaf(sH[grp][0][j + 32], w.y, g0);
        g1 = fmaf(sH[grp][1][j], w.x, g1);
        g1 = fmaf(sH[grp][1][j + 32], w.y, g1);
    }
    gp[((size_t)n * NCHUNK + tc) * 32 + lane] = make_float2(g0, g1);
}

// ---------------------------------------------------------------------------
// Kernel 6 (layer 2 aggregation): same decomposition; per-XCD working set
// gp-slice 0.64 MB + edges 1.28 MB. One float2 load per edge.
// ---------------------------------------------------------------------------
__global__ __launch_bounds__(256) void layer2_kernel(
    const float2* __restrict__ gp,
    const int* __restrict__ rowptr,
    const int2* __restrict__ edges,
    const float* __restrict__ selfn,
    const float* __restrict__ b2,
    float* __restrict__ out, int out_size) {
    int b = blockIdx.x;
    int tc = b & (NCHUNK - 1);
    int nb = b >> 3;
    int tid = threadIdx.x;
    int grp = tid >> 5;
    int lane = tid & 31;
    int n = nb * GPB + grp;

    const float2* gq = gp + tc * 32 + lane;   // index with [c * 256]

    float sn = selfn[n];
    float bb = b2[lane];
    float2 gs = gq[(size_t)n * (NCHUNK * 32)];
    float a0 = fmaf(sn, gs.x, bb);
    float a1 = fmaf(sn, gs.y, bb);

    int e0 = rowptr[n];
    int len = rowptr[n + 1] - e0;
    const int2* E = edges + e0;
    GATHER_LOOP(E, gq)

    int t0 = tc * TB;
    out[(size_t)t0 * NF + n * FIN + lane] = a0;
    out[(size_t)t0 * NF + NF + n * FIN + lane] = a1;

    // second tuple element (scalar 0) and any tail
    if (b == 0 && tid == 0) {
        for (int i = T_DIM * NF; i < out_size; ++i) out[i] = 0.0f;
    }
}

// ---------------------------------------------------------------------------
extern "C" void kernel_launch(void* const* d_in, const int* in_sizes, int n_in,
                              void* d_out, int out_size, void* d_ws, size_t ws_size,
                              hipStream_t stream) {
    const float* x  = (const float*)d_in[0];
    const int*   ei = (const int*)d_in[1];     // (2, E) int32: [src | dst]
    const float* w  = (const float*)d_in[2];
    // d_in[3] missing_mask: unused by reference math
    const float* W1 = (const float*)d_in[4];
    const float* b1 = (const float*)d_in[5];
    const float* W2 = (const float*)d_in[6];
    const float* b2 = (const float*)d_in[7];
    float* out = (float*)d_out;

    char* p = (char*)d_ws;
    float2* xp    = (float2*)p; p += sizeof(float2) * (size_t)N_NODES * NCHUNK * 32;
    float2* gp    = (float2*)p; p += sizeof(float2) * (size_t)N_NODES * NCHUNK * 32;
    // deg, cnt, cursor contiguous -> single memset
    float* deg    = (float*)p; p += sizeof(float) * N_NODES;
    int*   cnt    = (int*)p;   p += sizeof(int) * N_NODES;
    int*   cursor = (int*)p;   p += sizeof(int) * N_NODES;
    float* dis    = (float*)p; p += sizeof(float) * N_NODES;
    float* selfn  = (float*)p; p += sizeof(float) * N_NODES;
    int*   rowptr = (int*)p;   p += sizeof(int) * (N_NODES + 1);
    int2*  edges  = (int2*)p;  p += sizeof(int2) * NE;
    float2* W1p   = (float2*)p; p += sizeof(float2) * FIN * 32;
    float2* W2p   = (float2*)p; p += sizeof(float2) * 32 * FIN;

    hipMemsetAsync(deg, 0, sizeof(float) * N_NODES * 3, stream);

    build_deg_kernel<<<(NE + 255) / 256, 256, 0, stream>>>(ei, w, deg, cnt);
    mid_kernel<<<13, 1024, 0, stream>>>(deg, dis, selfn, cnt, rowptr,
                                        W1, W2, W1p, W2p);
    build_csr_kernel<<<(NE + 255) / 256, 256, 0, stream>>>(ei, w, dis, rowptr,
                                                           cursor, edges);
    transpose_kernel<<<(N_NODES / GPB) * NCHUNK, 256, 0, stream>>>(x, xp);
    layer1_kernel<<<(N_NODES / GPB) * NCHUNK, 256, 0, stream>>>(
        xp, rowptr, edges, selfn, W1p, b1, W2p, gp);
    layer2_kernel<<<(N_NODES / GPB) * NCHUNK, 256, 0, stream>>>(
        gp, rowptr, edges, selfn, b2, out, out_size);
}

// Round 6
// 293.979 us; speedup vs baseline: 1.0288x; 1.0288x over previous
//
#include <hip/hip_runtime.h>
#include <hip/hip_bf16.h>

// Problem constants (from reference)
#define T_DIM   16
#define N_NODES 10000
#define FIN     32
#define FH      64
#define NE      160000
#define GPB     8              // 32-lane groups per 256-thread block
#define TB      2              // timesteps per chunk
#define NCHUNK  (T_DIM / TB)   // 8 chunks -> one per XCD via bid%8
#define NF      (N_NODES * FIN)

// ---------------------------------------------------------------------------
// Kernel 1: degree (float, weighted, over dst) + in-edge count histogram
// ---------------------------------------------------------------------------
__global__ void build_deg_kernel(const int* __restrict__ ei,
                                 const float* __restrict__ w,
                                 float* __restrict__ deg,
                                 int* __restrict__ cnt) {
    int e = blockIdx.x * blockDim.x + threadIdx.x;
    if (e < NE) {
        int d = ei[NE + e];          // dst row of edge_index (2, E)
        atomicAdd(&deg[d], w[e]);
        atomicAdd(&cnt[d], 1);
    }
}

// ---------------------------------------------------------------------------
// Kernel 2 (merged): blocks 0-9 finish_deg; block 10 exclusive scan;
// blocks 11-12 pack W1/W2 into per-lane float2 column pairs.
// W1p[f*32+l] = {W1[f][l], W1[f][l+32]}   (f<32, l<32)
// W2p[j*32+l] = {W2[j][l], W2[j+32][l]}   (j<32, l<32)
// ---------------------------------------------------------------------------
__global__ __launch_bounds__(1024) void mid_kernel(
    const float* __restrict__ deg, float* __restrict__ dis,
    float* __restrict__ selfn,
    const int* __restrict__ cnt, int* __restrict__ rowptr,
    const float* __restrict__ W1, const float* __restrict__ W2,
    float2* __restrict__ W1p, float2* __restrict__ W2p) {
    __shared__ int sm[1024];
    int b = blockIdx.x;
    int tid = threadIdx.x;
    if (b < 10) {                       // dis / selfnorm
        int n = b * 1024 + tid;
        if (n < N_NODES) {
            float d = deg[n] + 1.0f;    // + self-loop weight
            float r = rsqrtf(d);
            dis[n] = r;
            selfn[n] = r * r;
        }
    } else if (b == 10) {               // exclusive scan cnt -> rowptr
        int base = tid * 10;
        int v[10];
        int s = 0;
#pragma unroll
        for (int k = 0; k < 10; ++k) {
            int i = base + k;
            v[k] = (i < N_NODES) ? cnt[i] : 0;
            s += v[k];
        }
        sm[tid] = s;
        __syncthreads();
        for (int off = 1; off < 1024; off <<= 1) {
            int t = (tid >= off) ? sm[tid - off] : 0;
            __syncthreads();
            sm[tid] += t;
            __syncthreads();
        }
        int run = (tid > 0) ? sm[tid - 1] : 0;
#pragma unroll
        for (int k = 0; k < 10; ++k) {
            int i = base + k;
            if (i <= N_NODES) rowptr[i] = run;
            run += v[k];
        }
    } else if (b == 11) {
        int f = tid >> 5, l = tid & 31;
        W1p[tid] = make_float2(W1[f * FH + l], W1[f * FH + 32 + l]);
    } else {
        int j = tid >> 5, l = tid & 31;
        W2p[tid] = make_float2(W2[j * FIN + l], W2[(j + 32) * FIN + l]);
    }
}

// ---------------------------------------------------------------------------
// Kernel 3: scatter edges into dst-sorted CSR, packed {col, norm-bits}
// ---------------------------------------------------------------------------
__global__ void build_csr_kernel(const int* __restrict__ ei,
                                 const float* __restrict__ w,
                                 const float* __restrict__ dis,
                                 const int* __restrict__ rowptr,
                                 int* __restrict__ cursor,
                                 int2* __restrict__ edges) {
    int e = blockIdx.x * blockDim.x + threadIdx.x;
    if (e < NE) {
        int s = ei[e];
        int d = ei[NE + e];
        int pos = rowptr[d] + atomicAdd(&cursor[d], 1);
        edges[pos] = make_int2(s, __float_as_int(dis[s] * w[e] * dis[d]));
    }
}

// ---------------------------------------------------------------------------
// Kernel 4 (fused layer 1): block = (t-chunk tc, node-block nb),
// blockIdx = nb*8 + tc pins chunk->XCD (per-XCD x slice 2.56 MB < 4 MB L2).
// One 32-lane group (= half wave) per node, TB=2 timesteps in registers.
// Gather: direct x rows (stride 128 B -> full L1-set/L2-channel spread),
// 4-edge unroll with software-pipelined edge prefetch.
// Dense: global packed float2 weights (L1-resident) + 6 KB wave-private
// LDS for sAcc/sH broadcasts -> NO barriers.
// ---------------------------------------------------------------------------
__global__ __launch_bounds__(256) void layer1_kernel(
    const float* __restrict__ x,
    const int* __restrict__ rowptr,
    const int2* __restrict__ edges,
    const float* __restrict__ selfn,
    const float2* __restrict__ W1p,
    const float* __restrict__ b1,
    const float2* __restrict__ W2p,
    float2* __restrict__ gp) {
    __shared__ float sAcc[GPB][TB][FIN];   // 2 KB
    __shared__ float sH[GPB][TB][FH];      // 4 KB

    int b = blockIdx.x;
    int tc = b & (NCHUNK - 1);
    int nb = b >> 3;
    int tid = threadIdx.x;
    int grp = tid >> 5;
    int lane = tid & 31;
    int n = nb * GPB + grp;

    const float* x0 = x + (size_t)(tc * TB) * NF;   // slice t0; t0+1 at +NF

    float sn = selfn[n];
    float a0 = sn * x0[n * FIN + lane];
    float a1 = sn * x0[NF + n * FIN + lane];

    int e0 = rowptr[n];
    int len = rowptr[n + 1] - e0;
    const int2* E = edges + e0;

#define L1FMA(P) { int off = (P).x * FIN + lane;                        \
                   float vv = __int_as_float((P).y);                    \
                   a0 = fmaf(vv, x0[off], a0);                          \
                   a1 = fmaf(vv, x0[NF + off], a1); }
    {
        int i = 0;
        int2 c0, c1, c2, c3;
        if (4 <= len) { c0 = E[0]; c1 = E[1]; c2 = E[2]; c3 = E[3]; }
        for (; i + 8 <= len; i += 4) {
            int2 n0 = E[i + 4], n1 = E[i + 5], n2 = E[i + 6], n3 = E[i + 7];
            L1FMA(c0) L1FMA(c1) L1FMA(c2) L1FMA(c3)
            c0 = n0; c1 = n1; c2 = n2; c3 = n3;
        }
        if (i + 4 <= len) { L1FMA(c0) L1FMA(c1) L1FMA(c2) L1FMA(c3) i += 4; }
        for (; i < len; ++i) { int2 p = E[i]; L1FMA(p) }
    }
#undef L1FMA

    // ---- dense: h = relu(acc @ W1 + b1); g = h @ W2 ----
    sAcc[grp][0][lane] = a0;
    sAcc[grp][1][lane] = a1;
    float h0 = b1[lane];
    float h1 = b1[lane + 32];
    float h2 = h0, h3 = h1;
#pragma unroll
    for (int f = 0; f < FIN; ++f) {
        float2 w = W1p[f * 32 + lane];
        float af0 = sAcc[grp][0][f];   // same-wave LDS broadcast
        float af1 = sAcc[grp][1][f];
        h0 = fmaf(af0, w.x, h0); h1 = fmaf(af0, w.y, h1);
        h2 = fmaf(af1, w.x, h2); h3 = fmaf(af1, w.y, h3);
    }
    sH[grp][0][lane] = fmaxf(h0, 0.0f);
    sH[grp][0][lane + 32] = fmaxf(h1, 0.0f);
    sH[grp][1][lane] = fmaxf(h2, 0.0f);
    sH[grp][1][lane + 32] = fmaxf(h3, 0.0f);
    float g0 = 0.0f, g1 = 0.0f;
#pragma unroll
    for (int j = 0; j < 32; ++j) {
        float2 w = W2p[j * 32 + lane];
        g0 = fmaf(sH[grp][0][j], w.x, g0);
        g0 = fmaf(sH[grp][0][j + 32], w.y, g0);
        g1 = fmaf(sH[grp][1][j], w.x, g1);
        g1 = fmaf(sH[grp][1][j + 32], w.y, g1);
    }
    // chunk-major: gp[tc][n][lane] -> node stride 256 B (no 2 KB pathology)
    gp[(size_t)tc * (N_NODES * 32) + n * 32 + lane] = make_float2(g0, g1);
}

// ---------------------------------------------------------------------------
// Kernel 5 (layer 2 aggregation): same decomposition; chunk-major gp gives
// ONE float2 load per edge at node stride 256 B, XCD-local (written by the
// same chunk's blocks in layer1). out (T,N,F) + b2.
// ---------------------------------------------------------------------------
__global__ __launch_bounds__(256) void layer2_kernel(
    const float2* __restrict__ gp,
    const int* __restrict__ rowptr,
    const int2* __restrict__ edges,
    const float* __restrict__ selfn,
    const float* __restrict__ b2,
    float* __restrict__ out, int out_size) {
    int b = blockIdx.x;
    int tc = b & (NCHUNK - 1);
    int nb = b >> 3;
    int tid = threadIdx.x;
    int grp = tid >> 5;
    int lane = tid & 31;
    int n = nb * GPB + grp;

    const float2* gq = gp + (size_t)tc * (N_NODES * 32) + lane;  // [c*32]

    float sn = selfn[n];
    float bb = b2[lane];
    float2 gs = gq[n * 32];
    float a0 = fmaf(sn, gs.x, bb);
    float a1 = fmaf(sn, gs.y, bb);

    int e0 = rowptr[n];
    int len = rowptr[n + 1] - e0;
    const int2* E = edges + e0;

#define L2FMA(P) { float2 vv = gq[(P).x * 32];                          \
                   float ww = __int_as_float((P).y);                    \
                   a0 = fmaf(ww, vv.x, a0);                             \
                   a1 = fmaf(ww, vv.y, a1); }
    {
        int i = 0;
        int2 c0, c1, c2, c3;
        if (4 <= len) { c0 = E[0]; c1 = E[1]; c2 = E[2]; c3 = E[3]; }
        for (; i + 8 <= len; i += 4) {
            int2 n0 = E[i + 4], n1 = E[i + 5], n2 = E[i + 6], n3 = E[i + 7];
            L2FMA(c0) L2FMA(c1) L2FMA(c2) L2FMA(c3)
            c0 = n0; c1 = n1; c2 = n2; c3 = n3;
        }
        if (i + 4 <= len) { L2FMA(c0) L2FMA(c1) L2FMA(c2) L2FMA(c3) i += 4; }
        for (; i < len; ++i) { int2 p = E[i]; L2FMA(p) }
    }
#undef L2FMA

    int t0 = tc * TB;
    out[(size_t)t0 * NF + n * FIN + lane] = a0;
    out[(size_t)t0 * NF + NF + n * FIN + lane] = a1;

    // second tuple element (scalar 0) and any tail
    if (b == 0 && tid == 0) {
        for (int i = T_DIM * NF; i < out_size; ++i) out[i] = 0.0f;
    }
}

// ---------------------------------------------------------------------------
extern "C" void kernel_launch(void* const* d_in, const int* in_sizes, int n_in,
                              void* d_out, int out_size, void* d_ws, size_t ws_size,
                              hipStream_t stream) {
    const float* x  = (const float*)d_in[0];
    const int*   ei = (const int*)d_in[1];     // (2, E) int32: [src | dst]
    const float* w  = (const float*)d_in[2];
    // d_in[3] missing_mask: unused by reference math
    const float* W1 = (const float*)d_in[4];
    const float* b1 = (const float*)d_in[5];
    const float* W2 = (const float*)d_in[6];
    const float* b2 = (const float*)d_in[7];
    float* out = (float*)d_out;

    char* p = (char*)d_ws;
    float2* gp    = (float2*)p; p += sizeof(float2) * (size_t)N_NODES * NCHUNK * 32;
    // deg, cnt, cursor contiguous -> single memset
    float* deg    = (float*)p; p += sizeof(float) * N_NODES;
    int*   cnt    = (int*)p;   p += sizeof(int) * N_NODES;
    int*   cursor = (int*)p;   p += sizeof(int) * N_NODES;
    float* dis    = (float*)p; p += sizeof(float) * N_NODES;
    float* selfn  = (float*)p; p += sizeof(float) * N_NODES;
    int*   rowptr = (int*)p;   p += sizeof(int) * (N_NODES + 1);
    int2*  edges  = (int2*)p;  p += sizeof(int2) * NE;
    float2* W1p   = (float2*)p; p += sizeof(float2) * FIN * 32;
    float2* W2p   = (float2*)p; p += sizeof(float2) * 32 * FIN;

    hipMemsetAsync(deg, 0, sizeof(float) * N_NODES * 3, stream);

    build_deg_kernel<<<(NE + 255) / 256, 256, 0, stream>>>(ei, w, deg, cnt);
    mid_kernel<<<13, 1024, 0, stream>>>(deg, dis, selfn, cnt, rowptr,
                                        W1, W2, W1p, W2p);
    build_csr_kernel<<<(NE + 255) / 256, 256, 0, stream>>>(ei, w, dis, rowptr,
                                                           cursor, edges);
    layer1_kernel<<<(N_NODES / GPB) * NCHUNK, 256, 0, stream>>>(
        x, rowptr, edges, selfn, W1p, b1, W2p, gp);
    layer2_kernel<<<(N_NODES / GPB) * NCHUNK, 256, 0, stream>>>(
        gp, rowptr, edges, selfn, b2, out, out_size);
}

// Round 7
// 227.983 us; speedup vs baseline: 1.3266x; 1.2895x over previous
//
#include <hip/hip_runtime.h>
#include <hip/hip_bf16.h>

// Problem constants (from reference)
#define T_DIM   16
#define N_NODES 10000
#define FIN     32
#define FH      64
#define NE      160000
#define GPB     8              // 32-lane groups per 256-thread block
#define TB      2              // timesteps per chunk
#define NCHUNK  (T_DIM / TB)   // 8 chunks -> one per XCD via bid%8
#define NF      (N_NODES * FIN)

// ---------------------------------------------------------------------------
// Kernel 1: weighted degree histogram over dst + per-edge slot within row
// ---------------------------------------------------------------------------
__global__ void build_deg_kernel(const int* __restrict__ ei,
                                 const float* __restrict__ w,
                                 float* __restrict__ deg,
                                 int* __restrict__ cnt,
                                 int* __restrict__ slot) {
    int e = blockIdx.x * blockDim.x + threadIdx.x;
    if (e < NE) {
        int d = ei[NE + e];          // dst row of edge_index (2, E)
        atomicAdd(&deg[d], w[e]);
        slot[e] = atomicAdd(&cnt[d], 1);
    }
}

// ---------------------------------------------------------------------------
// Kernel 2 (merged): blocks 0-9 finish_deg; block 10 exclusive scan;
// blocks 11-12 pack W1/W2 into per-lane float2 column pairs.
// W1p[f*32+l] = {W1[f][l], W1[f][l+32]}   (f<32, l<32)
// W2p[j*32+l] = {W2[j][l], W2[j+32][l]}   (j<32, l<32)
// ---------------------------------------------------------------------------
__global__ __launch_bounds__(1024) void mid_kernel(
    const float* __restrict__ deg, float* __restrict__ dis,
    float* __restrict__ selfn,
    const int* __restrict__ cnt, int* __restrict__ rowptr,
    const float* __restrict__ W1, const float* __restrict__ W2,
    float2* __restrict__ W1p, float2* __restrict__ W2p) {
    __shared__ int sm[1024];
    int b = blockIdx.x;
    int tid = threadIdx.x;
    if (b < 10) {                       // dis / selfnorm
        int n = b * 1024 + tid;
        if (n < N_NODES) {
            float d = deg[n] + 1.0f;    // + self-loop weight
            float r = rsqrtf(d);
            dis[n] = r;
            selfn[n] = r * r;
        }
    } else if (b == 10) {               // exclusive scan cnt -> rowptr
        int base = tid * 10;
        int v[10];
        int s = 0;
#pragma unroll
        for (int k = 0; k < 10; ++k) {
            int i = base + k;
            v[k] = (i < N_NODES) ? cnt[i] : 0;
            s += v[k];
        }
        sm[tid] = s;
        __syncthreads();
        for (int off = 1; off < 1024; off <<= 1) {
            int t = (tid >= off) ? sm[tid - off] : 0;
            __syncthreads();
            sm[tid] += t;
            __syncthreads();
        }
        int run = (tid > 0) ? sm[tid - 1] : 0;
#pragma unroll
        for (int k = 0; k < 10; ++k) {
            int i = base + k;
            if (i <= N_NODES) rowptr[i] = run;
            run += v[k];
        }
    } else if (b == 11) {
        int f = tid >> 5, l = tid & 31;
        W1p[tid] = make_float2(W1[f * FH + l], W1[f * FH + 32 + l]);
    } else {
        int j = tid >> 5, l = tid & 31;
        W2p[tid] = make_float2(W2[j * FIN + l], W2[(j + 32) * FIN + l]);
    }
}

// ---------------------------------------------------------------------------
// Kernel 3: scatter edges into dst-sorted CSR, packed {col, norm-bits}
// (slot precomputed in build_deg -> no atomics here)
// ---------------------------------------------------------------------------
__global__ void build_csr_kernel(const int* __restrict__ ei,
                                 const float* __restrict__ w,
                                 const float* __restrict__ dis,
                                 const int* __restrict__ rowptr,
                                 const int* __restrict__ slot,
                                 int2* __restrict__ edges) {
    int e = blockIdx.x * blockDim.x + threadIdx.x;
    if (e < NE) {
        int s = ei[e];
        int d = ei[NE + e];
        int pos = rowptr[d] + slot[e];
        edges[pos] = make_int2(s, __float_as_int(dis[s] * w[e] * dis[d]));
    }
}

// ---------------------------------------------------------------------------
// Kernel 4 (fused layer 1): block = (t-chunk tc, node-block nb),
// blockIdx = nb*8 + tc pins chunk->XCD (per-XCD x slice 2.56 MB < 4 MB L2).
// One 32-lane group (= half wave) per node, TB=2 timesteps in registers.
// Weights LDS-staged (packed float2); the ONLY barrier is right after
// staging (before the gather) so divergent edge counts don't couple groups.
// Dense phase: LDS weights + wave-private sAcc/sH broadcasts, no barriers.
// ---------------------------------------------------------------------------
__global__ __launch_bounds__(256) void layer1_kernel(
    const float* __restrict__ x,
    const int* __restrict__ rowptr,
    const int2* __restrict__ edges,
    const float* __restrict__ selfn,
    const float2* __restrict__ W1p,
    const float* __restrict__ b1,
    const float2* __restrict__ W2p,
    float2* __restrict__ gp) {
    __shared__ float2 sW1p[FIN * 32];      // 8 KB
    __shared__ float2 sW2p[32 * FIN];      // 8 KB
    __shared__ float sB1[FH];              // 256 B
    __shared__ float sAcc[GPB][TB][FIN];   // 2 KB
    __shared__ float sH[GPB][TB][FH];      // 4 KB

    int tid = threadIdx.x;
#pragma unroll
    for (int i = 0; i < 4; ++i) sW1p[tid + i * 256] = W1p[tid + i * 256];
#pragma unroll
    for (int i = 0; i < 4; ++i) sW2p[tid + i * 256] = W2p[tid + i * 256];
    if (tid < FH) sB1[tid] = b1[tid];
    __syncthreads();                       // staging visible; groups decouple

    int b = blockIdx.x;
    int tc = b & (NCHUNK - 1);
    int nb = b >> 3;
    int grp = tid >> 5;
    int lane = tid & 31;
    int n = nb * GPB + grp;

    const float* x0 = x + (size_t)(tc * TB) * NF;   // slice t0; t0+1 at +NF

    float sn = selfn[n];
    float a0 = sn * x0[n * FIN + lane];
    float a1 = sn * x0[NF + n * FIN + lane];

    int e = rowptr[n], e1 = rowptr[n + 1];
    for (; e + 4 <= e1; e += 4) {
        int2 p0 = edges[e], p1 = edges[e + 1], p2 = edges[e + 2], p3 = edges[e + 3];
        int c0 = p0.x * FIN + lane, c1 = p1.x * FIN + lane;
        int c2 = p2.x * FIN + lane, c3 = p3.x * FIN + lane;
        float x00 = x0[c0], x01 = x0[NF + c0];
        float x10 = x0[c1], x11 = x0[NF + c1];
        float x20 = x0[c2], x21 = x0[NF + c2];
        float x30 = x0[c3], x31 = x0[NF + c3];
        float v0 = __int_as_float(p0.y), v1 = __int_as_float(p1.y);
        float v2 = __int_as_float(p2.y), v3 = __int_as_float(p3.y);
        a0 = fmaf(v0, x00, a0); a1 = fmaf(v0, x01, a1);
        a0 = fmaf(v1, x10, a0); a1 = fmaf(v1, x11, a1);
        a0 = fmaf(v2, x20, a0); a1 = fmaf(v2, x21, a1);
        a0 = fmaf(v3, x30, a0); a1 = fmaf(v3, x31, a1);
    }
    for (; e < e1; ++e) {
        int2 p = edges[e];
        float v = __int_as_float(p.y);
        int c = p.x * FIN + lane;
        a0 = fmaf(v, x0[c], a0);
        a1 = fmaf(v, x0[NF + c], a1);
    }

    // ---- dense: h = relu(acc @ W1 + b1); g = h @ W2  (no barriers) ----
    sAcc[grp][0][lane] = a0;
    sAcc[grp][1][lane] = a1;
    float h0 = sB1[lane];
    float h1 = sB1[lane + 32];
    float h2 = h0, h3 = h1;
#pragma unroll
    for (int f = 0; f < FIN; ++f) {
        float2 w = sW1p[f * 32 + lane];
        float af0 = sAcc[grp][0][f];   // same-wave LDS broadcast
        float af1 = sAcc[grp][1][f];
        h0 = fmaf(af0, w.x, h0); h1 = fmaf(af0, w.y, h1);
        h2 = fmaf(af1, w.x, h2); h3 = fmaf(af1, w.y, h3);
    }
    sH[grp][0][lane] = fmaxf(h0, 0.0f);
    sH[grp][0][lane + 32] = fmaxf(h1, 0.0f);
    sH[grp][1][lane] = fmaxf(h2, 0.0f);
    sH[grp][1][lane + 32] = fmaxf(h3, 0.0f);
    float g0 = 0.0f, g1 = 0.0f;
#pragma unroll
    for (int j = 0; j < 32; ++j) {
        float2 w = sW2p[j * 32 + lane];
        g0 = fmaf(sH[grp][0][j], w.x, g0);
        g0 = fmaf(sH[grp][0][j + 32], w.y, g0);
        g1 = fmaf(sH[grp][1][j], w.x, g1);
        g1 = fmaf(sH[grp][1][j + 32], w.y, g1);
    }
    // chunk-major: gp[tc][n][lane] -> node stride 256 B
    gp[(size_t)tc * (N_NODES * 32) + n * 32 + lane] = make_float2(g0, g1);
}

// ---------------------------------------------------------------------------
// Kernel 5 (layer 2 aggregation): same decomposition; chunk-major gp gives
// ONE float2 load per edge at node stride 256 B, XCD-local. out (T,N,F) + b2.
// ---------------------------------------------------------------------------
__global__ __launch_bounds__(256) void layer2_kernel(
    const float2* __restrict__ gp,
    const int* __restrict__ rowptr,
    const int2* __restrict__ edges,
    const float* __restrict__ selfn,
    const float* __restrict__ b2,
    float* __restrict__ out, int out_size) {
    int b = blockIdx.x;
    int tc = b & (NCHUNK - 1);
    int nb = b >> 3;
    int tid = threadIdx.x;
    int grp = tid >> 5;
    int lane = tid & 31;
    int n = nb * GPB + grp;

    const float2* gq = gp + (size_t)tc * (N_NODES * 32) + lane;  // [c*32]

    float sn = selfn[n];
    float bb = b2[lane];
    float2 gs = gq[n * 32];
    float a0 = fmaf(sn, gs.x, bb);
    float a1 = fmaf(sn, gs.y, bb);

    int e = rowptr[n], e1 = rowptr[n + 1];
    for (; e + 4 <= e1; e += 4) {
        int2 p0 = edges[e], p1 = edges[e + 1], p2 = edges[e + 2], p3 = edges[e + 3];
        float2 q0 = gq[p0.x * 32], q1 = gq[p1.x * 32];
        float2 q2 = gq[p2.x * 32], q3 = gq[p3.x * 32];
        float v0 = __int_as_float(p0.y), v1 = __int_as_float(p1.y);
        float v2 = __int_as_float(p2.y), v3 = __int_as_float(p3.y);
        a0 = fmaf(v0, q0.x, a0); a1 = fmaf(v0, q0.y, a1);
        a0 = fmaf(v1, q1.x, a0); a1 = fmaf(v1, q1.y, a1);
        a0 = fmaf(v2, q2.x, a0); a1 = fmaf(v2, q2.y, a1);
        a0 = fmaf(v3, q3.x, a0); a1 = fmaf(v3, q3.y, a1);
    }
    for (; e < e1; ++e) {
        int2 p = edges[e];
        float v = __int_as_float(p.y);
        float2 q = gq[p.x * 32];
        a0 = fmaf(v, q.x, a0);
        a1 = fmaf(v, q.y, a1);
    }

    int t0 = tc * TB;
    out[(size_t)t0 * NF + n * FIN + lane] = a0;
    out[(size_t)t0 * NF + NF + n * FIN + lane] = a1;

    // second tuple element (scalar 0) and any tail
    if (b == 0 && tid == 0) {
        for (int i = T_DIM * NF; i < out_size; ++i) out[i] = 0.0f;
    }
}

// ---------------------------------------------------------------------------
extern "C" void kernel_launch(void* const* d_in, const int* in_sizes, int n_in,
                              void* d_out, int out_size, void* d_ws, size_t ws_size,
                              hipStream_t stream) {
    const float* x  = (const float*)d_in[0];
    const int*   ei = (const int*)d_in[1];     // (2, E) int32: [src | dst]
    const float* w  = (const float*)d_in[2];
    // d_in[3] missing_mask: unused by reference math
    const float* W1 = (const float*)d_in[4];
    const float* b1 = (const float*)d_in[5];
    const float* W2 = (const float*)d_in[6];
    const float* b2 = (const float*)d_in[7];
    float* out = (float*)d_out;

    char* p = (char*)d_ws;
    float2* gp    = (float2*)p; p += sizeof(float2) * (size_t)N_NODES * NCHUNK * 32;
    // deg, cnt contiguous -> single memset
    float* deg    = (float*)p; p += sizeof(float) * N_NODES;
    int*   cnt    = (int*)p;   p += sizeof(int) * N_NODES;
    float* dis    = (float*)p; p += sizeof(float) * N_NODES;
    float* selfn  = (float*)p; p += sizeof(float) * N_NODES;
    int*   rowptr = (int*)p;   p += sizeof(int) * (N_NODES + 1);
    int*   slot   = (int*)p;   p += sizeof(int) * NE;
    int2*  edges  = (int2*)p;  p += sizeof(int2) * NE;
    float2* W1p   = (float2*)p; p += sizeof(float2) * FIN * 32;
    float2* W2p   = (float2*)p; p += sizeof(float2) * 32 * FIN;

    hipMemsetAsync(deg, 0, sizeof(float) * N_NODES * 2, stream);

    build_deg_kernel<<<(NE + 255) / 256, 256, 0, stream>>>(ei, w, deg, cnt, slot);
    mid_kernel<<<13, 1024, 0, stream>>>(deg, dis, selfn, cnt, rowptr,
                                        W1, W2, W1p, W2p);
    build_csr_kernel<<<(NE + 255) / 256, 256, 0, stream>>>(ei, w, dis, rowptr,
                                                           slot, edges);
    layer1_kernel<<<(N_NODES / GPB) * NCHUNK, 256, 0, stream>>>(
        x, rowptr, edges, selfn, W1p, b1, W2p, gp);
    layer2_kernel<<<(N_NODES / GPB) * NCHUNK, 256, 0, stream>>>(
        gp, rowptr, edges, selfn, b2, out, out_size);
}